// Round 1
// baseline (160.165 us; speedup 1.0000x reference)
//
#include <hip/hip_runtime.h>

#define ROWS   32768      // 8*4096 indices
#define DIM4   128        // 512 floats per row = 128 float4
#define BLOCK  256

__global__ __launch_bounds__(BLOCK) void embed_gather_kernel(
    const int* __restrict__ idx,
    const float4* __restrict__ W,
    float4* __restrict__ out)
{
    const int tid = blockIdx.x * BLOCK + threadIdx.x;   // one float4 per thread
    const int row = tid >> 7;      // which of the 32768 output rows
    const int col = tid & (DIM4 - 1);
    const int id  = idx[row];      // wave-uniform (64 lanes cover half a row)
    out[tid] = W[(size_t)id * DIM4 + col];
}

extern "C" void kernel_launch(void* const* d_in, const int* in_sizes, int n_in,
                              void* d_out, int out_size, void* d_ws, size_t ws_size,
                              hipStream_t stream) {
    const int*    idx = (const int*)d_in[0];
    const float4* W   = (const float4*)d_in[1];
    float4*       out = (float4*)d_out;

    const int total4 = ROWS * DIM4;           // 4,194,304 float4 == out_size/4
    const int grid   = total4 / BLOCK;        // 16384 blocks, exact
    embed_gather_kernel<<<grid, BLOCK, 0, stream>>>(idx, W, out);
}